// Round 1
// baseline (72.183 us; speedup 1.0000x reference)
//
#include <hip/hip_runtime.h>

// EctLayer: ect[b,r,t] = sum_{n: batch[n]==b} sigmoid(SCALE*(lin[r] - (x[n]·dir[:,t])))
// N=65536, D=3, T=64, R=64, B=64. SCALE=500.
//
// Design: grid of N/TILE blocks, TILE=64 consecutive points per block.
//  - stage x-tile, dirs, batch-tile in LDS; compute nh[p][t] tile in LDS.
//  - 256 threads: thread owns t = tid&63 and 16 r values (rbase = (tid>>6)*16),
//    accumulates 16 cells in registers.
//  - batch sorted => flush (atomicAdd to out) only when segment id changes
//    within the tile, plus once at the end. ~4.3M atomics total.
//  - sigmoid = rcp(1 + exp(500*nh - 500*lin[r])); hardware exp/rcp saturate
//    correctly at +-inf so no branches needed.

#define N_PTS   65536
#define DIMS    3
#define T_DIRS  64
#define R_STEPS 64
#define TILE    64
#define THREADS 256
#define SCALE_F 500.0f

__global__ __launch_bounds__(THREADS) void ect_kernel(
    const float* __restrict__ x,      // [N,3]
    const float* __restrict__ dirs,   // [3,T]
    const float* __restrict__ lin,    // [R]
    const int*   __restrict__ batch,  // [N] sorted, values in [0,B)
    float* __restrict__ out)          // [B,R,T], pre-zeroed
{
    __shared__ float s_nh[TILE * T_DIRS];   // 16 KiB: nh[p][t]
    __shared__ float s_x[TILE * DIMS];
    __shared__ float s_dir[DIMS * T_DIRS];
    __shared__ int   s_batch[TILE];

    const int tid  = threadIdx.x;
    const int base = blockIdx.x * TILE;

    if (tid < DIMS * T_DIRS)  s_dir[tid] = dirs[tid];
    if (tid < TILE * DIMS)    s_x[tid]   = x[base * DIMS + tid];
    if (tid < TILE)           s_batch[tid] = batch[base + tid];

    const int t     = tid & (T_DIRS - 1);
    const int rbase = (tid >> 6) * 16;      // 4 groups of 16 r values

    // c[i] = SCALE * lin[rbase+i]  (tiny global reads, L2-resident)
    float c[16];
#pragma unroll
    for (int i = 0; i < 16; ++i)
        c[i] = SCALE_F * lin[rbase + i];

    __syncthreads();

    // phase A: nh[p][t] = x[p,:]·dir[:,t]   (4096 values, 16 per thread)
#pragma unroll
    for (int k = 0; k < (TILE * T_DIRS) / THREADS; ++k) {
        int idx = tid + k * THREADS;
        int p   = idx >> 6;        // / T_DIRS
        int tt  = idx & (T_DIRS - 1);
        float v = s_x[p * 3 + 0] * s_dir[0 * T_DIRS + tt]
                + s_x[p * 3 + 1] * s_dir[1 * T_DIRS + tt]
                + s_x[p * 3 + 2] * s_dir[2 * T_DIRS + tt];
        s_nh[idx] = v;
    }
    __syncthreads();

    float acc[16];
#pragma unroll
    for (int i = 0; i < 16; ++i) acc[i] = 0.0f;

    int cur_b = s_batch[0];

    for (int p = 0; p < TILE; ++p) {
        int b = s_batch[p];                 // uniform across block
        if (b != cur_b) {                   // segment boundary: flush
#pragma unroll
            for (int i = 0; i < 16; ++i) {
                atomicAdd(&out[cur_b * (R_STEPS * T_DIRS) + (rbase + i) * T_DIRS + t], acc[i]);
                acc[i] = 0.0f;
            }
            cur_b = b;
        }
        float h500 = SCALE_F * s_nh[p * T_DIRS + t];  // stride-1 LDS read
#pragma unroll
        for (int i = 0; i < 16; ++i) {
            // sigmoid(500*(lin - nh)) = 1 / (1 + exp(500*nh - 500*lin))
            float e = __expf(h500 - c[i]);                 // v_mul + v_exp_f32
            acc[i] += __builtin_amdgcn_rcpf(1.0f + e);     // v_rcp_f32, rcp(inf)=0
        }
    }

#pragma unroll
    for (int i = 0; i < 16; ++i)
        atomicAdd(&out[cur_b * (R_STEPS * T_DIRS) + (rbase + i) * T_DIRS + t], acc[i]);
}

extern "C" void kernel_launch(void* const* d_in, const int* in_sizes, int n_in,
                              void* d_out, int out_size, void* d_ws, size_t ws_size,
                              hipStream_t stream) {
    const float* x     = (const float*)d_in[0];
    const float* dirs  = (const float*)d_in[1];
    const float* lin   = (const float*)d_in[2];
    const int*   batch = (const int*)d_in[3];
    float* out = (float*)d_out;

    // out is poisoned by the harness; zero it (graph-capture-safe memset)
    hipMemsetAsync(out, 0, (size_t)out_size * sizeof(float), stream);

    dim3 grid(N_PTS / TILE);
    dim3 block(THREADS);
    ect_kernel<<<grid, block, 0, stream>>>(x, dirs, lin, batch, out);
}